// Round 6
// baseline (1316.011 us; speedup 1.0000x reference)
//
#include <hip/hip_runtime.h>
#include <hip/hip_cooperative_groups.h>

namespace cg = cooperative_groups;

// ---------------------------------------------------------------------------
// multitask MLP, MI355X bf16 MFMA — round 6
// r5 -> r6: fuse gather + 8 GEMM layers + head into ONE cooperative kernel
// (grid.sync between stages). GEMM tile internals unchanged from r5:
// 64x64x64 tile, 4 waves (32x32 each), 3-buf pipeline, vmcnt(4), XOR swizzle.
// Goals: (a) kill inter-kernel gaps, (b) make the hot loop visible in rocprof
// (single ~200us dispatch -> top-1 row with real counters).
// ---------------------------------------------------------------------------

typedef __attribute__((ext_vector_type(4))) float f32x4;
typedef __attribute__((ext_vector_type(8))) __bf16 bf16x8;
typedef __attribute__((ext_vector_type(4))) unsigned short u16x4;

#define AS1 __attribute__((address_space(1)))
#define AS3 __attribute__((address_space(3)))

static constexpr int B_  = 2048;
static constexpr int D_  = 1024;
static constexpr int T_  = 4;
static constexpr int H_  = 64;
static constexpr int MP_ = 2112;                    // B_ padded by 64 for tile overrun
static constexpr size_t MSZ = (size_t)D_ * D_;      // elems per DxD matrix (1M)

// ws layout (bytes)
static constexpr size_t OFF_PERM = 0;                         // 2048 int
static constexpr size_t OFF_SEG  = 8192;                      // 8 int
static constexpr size_t OFF_W    = 16384;                     // bf16 transposed weights
//   matrices 0..1: ws1 l0,l1 | 2..9: wt1 (t*2+l) | 10..11: ws2 | 12..19: wt2 (t*2+l)
//   then h1t: 4 * [64][1024]
static constexpr size_t H1T_ELEM_OFF = 20 * MSZ;
static constexpr size_t W_ELEMS  = 20 * MSZ + (size_t)T_ * H_ * D_;
static constexpr size_t OFF_XP   = OFF_W + W_ELEMS * 2;
static constexpr size_t ACT_BYTES = (size_t)MP_ * D_ * 2;
static constexpr size_t OFF_A0   = OFF_XP + ACT_BYTES;
static constexpr size_t OFF_A1   = OFF_A0 + ACT_BYTES;
static constexpr size_t WS_NEED  = OFF_A1 + ACT_BYTES;        // ~53 MiB

static __device__ __forceinline__ unsigned short f2bf(float f) {
    union { float f; unsigned int u; } v; v.f = f;
    unsigned int r = v.u + 0x7fffu + ((v.u >> 16) & 1u);      // RNE
    return (unsigned short)(r >> 16);
}

// ---------------------------------------------------------------------------
// 1) per-task segments + permutation (1 block)
// ---------------------------------------------------------------------------
__global__ void perm_kernel(const int* __restrict__ btask,
                            int* __restrict__ perm, int* __restrict__ seg) {
    __shared__ int cnt[T_], cur[T_];
    int tid = threadIdx.x;
    if (tid < T_) cnt[tid] = 0;
    __syncthreads();
    for (int i = tid; i < B_; i += 256) atomicAdd(&cnt[btask[i]], 1);
    __syncthreads();
    if (tid == 0) {
        int s = 0;
        for (int t = 0; t < T_; ++t) {
            seg[t] = s; seg[T_ + t] = cnt[t]; cur[t] = s; s += cnt[t];
        }
    }
    __syncthreads();
    for (int i = tid; i < B_; i += 256) {
        int t = btask[i];
        int p = atomicAdd(&cur[t], 1);
        perm[p] = i;
    }
}

// ---------------------------------------------------------------------------
// 2) fp32 -> bf16 transpose of all weight matrices.  z: matrix id 0..23.
// ---------------------------------------------------------------------------
__global__ __launch_bounds__(256)
void transpose_cvt(const float* __restrict__ ws1, const float* __restrict__ wt1,
                   const float* __restrict__ ws2, const float* __restrict__ wt2,
                   const float* __restrict__ h1, unsigned short* __restrict__ wb) {
    int z = blockIdx.z;
    const float* src; unsigned short* dst; int C = D_;
    if (z < 2)       { src = ws1 + (size_t)z * MSZ;        dst = wb + (size_t)z * MSZ; }
    else if (z < 10) { src = wt1 + (size_t)(z - 2) * MSZ;  dst = wb + (size_t)z * MSZ; }
    else if (z < 12) { src = ws2 + (size_t)(z - 10) * MSZ; dst = wb + (size_t)z * MSZ; }
    else if (z < 20) { src = wt2 + (size_t)(z - 12) * MSZ; dst = wb + (size_t)z * MSZ; }
    else { src = h1 + (size_t)(z - 20) * (D_ * H_);
           dst = wb + H1T_ELEM_OFF + (size_t)(z - 20) * (D_ * H_); C = H_; }
    int r0 = blockIdx.y * 64, c0 = blockIdx.x * 64;
    if (c0 >= C) return;
    __shared__ float tile[64][65];
    int tid = threadIdx.x;
#pragma unroll
    for (int i = 0; i < 4; ++i) {
        int idx = i * 256 + tid;
        int fr = idx >> 4, fc = (idx & 15) << 2;
        float4 v = *(const float4*)(src + (size_t)(r0 + fr) * C + c0 + fc);
        tile[fr][fc] = v.x; tile[fr][fc + 1] = v.y; tile[fr][fc + 2] = v.z; tile[fr][fc + 3] = v.w;
    }
    __syncthreads();
#pragma unroll
    for (int i = 0; i < 4; ++i) {
        int idx = i * 256 + tid;
        int orow = idx >> 4, ocb = (idx & 15) << 2;
        u16x4 o = { f2bf(tile[ocb][orow]),     f2bf(tile[ocb + 1][orow]),
                    f2bf(tile[ocb + 2][orow]), f2bf(tile[ocb + 3][orow]) };
        *(u16x4*)(dst + (size_t)(c0 + orow) * D_ + r0 + ocb) = o;
    }
}

// ---------------------------------------------------------------------------
// 3) fused network: gather -> 8 GEMM layers -> head.  512 blocks x 256 thr,
//    cooperative launch, grid.sync() between stages.  2 blocks/CU (48KB LDS).
// ---------------------------------------------------------------------------
__global__ __launch_bounds__(256, 2)
void fused_mlp(const float* x, const int* perm, const int* seg,
               const unsigned short* wb,
               const float* ws1b, const float* wt1b, const float* ws2b,
               const float* wt2b, const float* h1b, const float* h2w,
               const float* h2b,
               unsigned short* xp, unsigned short* a0, unsigned short* a1,
               float* out) {
    __shared__ unsigned short lA[3][4096];         // 3 x 8 KB
    __shared__ unsigned short lB[3][4096];         // 3 x 8 KB  (48 KB)
    cg::grid_group grid = cg::this_grid();

    const int bid = blockIdx.x;
    const int tid = threadIdx.x, wid = tid >> 6, lane = tid & 63;
    const int wm = wid >> 1, wn = wid & 1;
    const int l15 = lane & 15, l4 = lane >> 4;
    const int srow = lane >> 3;                    // 0..7 within staging chunk
    const int sslot = ((lane & 7) ^ srow) * 16;    // pre-swizzled source slot (bytes)

    // ---- stage 0: gather x into task-sorted order, fp32 -> bf16 ----
    {
        int g = bid * 256 + tid;                   // 131072 threads
#pragma unroll
        for (int k = 0; k < 4; ++k) {
            int flat = g + k * 131072;             // 524288 float4 total
            int row = flat >> 8, col = flat & 255;
            int src = perm[row];
            float4 v = ((const float4*)(x + (size_t)src * D_))[col];
            u16x4 o = { f2bf(v.x), f2bf(v.y), f2bf(v.z), f2bf(v.w) };
            ((u16x4*)(xp + (size_t)row * D_))[col] = o;
        }
    }
    __threadfence();
    grid.sync();

    // one 64x64 output tile: full K loop, r5-identical pipeline
    auto gemm_tile = [&](const unsigned short* A, const unsigned short* Wt,
                         const float* bs, unsigned short* Out,
                         int m0, int mend, int n0, bool relu) {
        f32x4 acc[2][2] = {};

        auto stage = [&](int kt, int buf) {
            const int k0 = kt * 64;
#pragma unroll
            for (int i = 0; i < 2; ++i) {
                int chunk = wid * 2 + i;
                int row = chunk * 8 + srow;
                const char* sa = (const char*)(A + (size_t)(m0 + row) * D_ + k0) + sslot;
                __builtin_amdgcn_global_load_lds((AS1 void*)sa,
                    (AS3 void*)(&lA[buf][0] + (size_t)chunk * 512), 16, 0, 0);
                const char* sb = (const char*)(Wt + (size_t)(n0 + row) * D_ + k0) + sslot;
                __builtin_amdgcn_global_load_lds((AS1 void*)sb,
                    (AS3 void*)(&lB[buf][0] + (size_t)chunk * 512), 16, 0, 0);
            }
        };
        auto compute = [&](int buf) {
            const unsigned short* bA = &lA[buf][0];
            const unsigned short* bB = &lB[buf][0];
#pragma unroll
            for (int kk = 0; kk < 2; ++kk) {
                const int swz = (((kk * 4) + l4) ^ (l15 & 7)) * 8;
                bf16x8 af[2], bfr[2];
#pragma unroll
                for (int m = 0; m < 2; ++m)
                    af[m] = *(const bf16x8*)(bA + (wm * 32 + m * 16 + l15) * 64 + swz);
#pragma unroll
                for (int n = 0; n < 2; ++n)
                    bfr[n] = *(const bf16x8*)(bB + (wn * 32 + n * 16 + l15) * 64 + swz);
#pragma unroll
                for (int m = 0; m < 2; ++m)
#pragma unroll
                    for (int n = 0; n < 2; ++n)
                        acc[m][n] = __builtin_amdgcn_mfma_f32_16x16x32_bf16(af[m], bfr[n], acc[m][n], 0, 0, 0);
            }
        };

        stage(0, 0);
        stage(1, 1);
        int bc = 0, bn2 = 2;
#pragma unroll 1
        for (int kt = 0; kt < 14; ++kt) {
            asm volatile("s_waitcnt vmcnt(4)" ::: "memory");
            __builtin_amdgcn_s_barrier();
            stage(kt + 2, bn2);
            compute(bc);
            bc  = (bc  == 2) ? 0 : bc  + 1;
            bn2 = (bn2 == 2) ? 0 : bn2 + 1;
        }
        asm volatile("s_waitcnt vmcnt(4)" ::: "memory");
        __builtin_amdgcn_s_barrier();
        compute(bc);
        bc = (bc == 2) ? 0 : bc + 1;
        asm volatile("s_waitcnt vmcnt(0)" ::: "memory");
        __builtin_amdgcn_s_barrier();
        compute(bc);

        // epilogue: C/D layout col=lane&15, row=(lane>>4)*4+j
#pragma unroll
        for (int n = 0; n < 2; ++n) {
            int col = n0 + wn * 32 + n * 16 + l15;
            float bv = bs[col];
#pragma unroll
            for (int m = 0; m < 2; ++m) {
                int rbase = m0 + wm * 32 + m * 16 + l4 * 4;
#pragma unroll
                for (int j = 0; j < 4; ++j) {
                    int row = rbase + j;
                    if (row < mend) {
                        float v = acc[m][n][j] + bv;
                        if (relu) v = fmaxf(v, 0.f);
                        Out[(size_t)row * D_ + col] = f2bf(v);
                    }
                }
            }
        }
        // barrier before the next tile reuses LDS buffers
        __builtin_amdgcn_s_barrier();
    };

    // ---- stages 1..8: the eight DxD layers ----
#pragma unroll 1
    for (int L = 0; L < 8; ++L) {
        const unsigned short* Wbase; const float* bbase;
        const unsigned short* Ain; unsigned short* Aout;
        bool istask, relu;
        switch (L) {
            case 0:  Wbase = wb;            bbase = ws1b;      Ain = xp; Aout = a0; istask = false; relu = true;  break;
            case 1:  Wbase = wb + 1 * MSZ;  bbase = ws1b + D_; Ain = a0; Aout = a1; istask = false; relu = true;  break;
            case 2:  Wbase = wb + 2 * MSZ;  bbase = wt1b;      Ain = a1; Aout = a0; istask = true;  relu = true;  break;
            case 3:  Wbase = wb + 3 * MSZ;  bbase = wt1b + D_; Ain = a0; Aout = a1; istask = true;  relu = false; break;
            case 4:  Wbase = wb + 10 * MSZ; bbase = ws2b;      Ain = a1; Aout = a0; istask = false; relu = true;  break;
            case 5:  Wbase = wb + 11 * MSZ; bbase = ws2b + D_; Ain = a0; Aout = a1; istask = false; relu = true;  break;
            case 6:  Wbase = wb + 12 * MSZ; bbase = wt2b;      Ain = a1; Aout = a0; istask = true;  relu = true;  break;
            default: Wbase = wb + 13 * MSZ; bbase = wt2b + D_; Ain = a0; Aout = a1; istask = true;  relu = true;  break;
        }
        const int vmax = istask ? 2048 : 512;
#pragma unroll 1
        for (int vt = bid; vt < vmax; vt += 512) {
            int m0, mend, n0;
            const unsigned short* Wl = Wbase; const float* bl = bbase;
            if (istask) {
                int t = vt >> 9, rem = vt & 511;
                n0 = (rem & 15) << 6;
                m0 = seg[t] + ((rem >> 4) << 6);
                mend = seg[t] + seg[4 + t];
                Wl += (size_t)t * (2 * MSZ);
                bl += (size_t)t * (2 * D_);
                if (m0 >= mend) continue;
            } else {
                m0 = (vt >> 4) << 6; n0 = (vt & 15) << 6; mend = B_;
            }
            gemm_tile(Ain, Wl, bl, Aout, m0, mend, n0, relu);
        }
        __threadfence();
        grid.sync();
    }

    // ---- stage 9: head  (A = a1, per-task H1t; sigmoid; scatter) ----
#pragma unroll 1
    for (int vt = bid; vt < 128; vt += 512) {
        int t = vt >> 5, mt = vt & 31;
        int s = seg[t], c = seg[4 + t];
        int m0 = s + mt * 64, mend = s + c;
        if (m0 >= mend) continue;
        const unsigned short* Ht = wb + H1T_ELEM_OFF + (size_t)t * (H_ * D_);
        f32x4 acc[4] = {};

        auto hstage = [&](int kt, int buf) {
            const int k0 = kt * 64;
#pragma unroll
            for (int i = 0; i < 2; ++i) {
                int chunk = wid * 2 + i;
                int row = chunk * 8 + srow;
                const char* sa = (const char*)(a1 + (size_t)(m0 + row) * D_ + k0) + sslot;
                __builtin_amdgcn_global_load_lds((AS1 void*)sa,
                    (AS3 void*)(&lA[buf][0] + (size_t)chunk * 512), 16, 0, 0);
                const char* sb = (const char*)(Ht + (size_t)row * D_ + k0) + sslot;
                __builtin_amdgcn_global_load_lds((AS1 void*)sb,
                    (AS3 void*)(&lB[buf][0] + (size_t)chunk * 512), 16, 0, 0);
            }
        };
        auto hcompute = [&](int buf) {
#pragma unroll
            for (int kk = 0; kk < 2; ++kk) {
                const int swz = (((kk * 4) + l4) ^ (l15 & 7)) * 8;
                bf16x8 af = *(const bf16x8*)(&lA[buf][0] + (wid * 16 + l15) * 64 + swz);
#pragma unroll
                for (int n = 0; n < 4; ++n) {
                    bf16x8 bfr = *(const bf16x8*)(&lB[buf][0] + (n * 16 + l15) * 64 + swz);
                    acc[n] = __builtin_amdgcn_mfma_f32_16x16x32_bf16(af, bfr, acc[n], 0, 0, 0);
                }
            }
        };

        hstage(0, 0);
        hstage(1, 1);
        int bc = 0, bn2 = 2;
#pragma unroll 1
        for (int kt = 0; kt < 14; ++kt) {
            asm volatile("s_waitcnt vmcnt(4)" ::: "memory");
            __builtin_amdgcn_s_barrier();
            hstage(kt + 2, bn2);
            hcompute(bc);
            bc  = (bc  == 2) ? 0 : bc  + 1;
            bn2 = (bn2 == 2) ? 0 : bn2 + 1;
        }
        asm volatile("s_waitcnt vmcnt(4)" ::: "memory");
        __builtin_amdgcn_s_barrier();
        hcompute(bc);
        bc = (bc == 2) ? 0 : bc + 1;
        asm volatile("s_waitcnt vmcnt(0)" ::: "memory");
        __builtin_amdgcn_s_barrier();
        hcompute(bc);

        float part[4] = {0.f, 0.f, 0.f, 0.f};
#pragma unroll
        for (int n = 0; n < 4; ++n) {
            int col = n * 16 + l15;
            float b1 = h1b[t * H_ + col];
            float w2 = h2w[t * H_ + col];
#pragma unroll
            for (int j = 0; j < 4; ++j) part[j] += (acc[n][j] + b1) * w2;
        }
#pragma unroll
        for (int msk = 1; msk < 16; msk <<= 1)
#pragma unroll
            for (int j = 0; j < 4; ++j) part[j] += __shfl_xor(part[j], msk);
        if (l15 == 0) {
            float b2 = h2b[t];
#pragma unroll
            for (int j = 0; j < 4; ++j) {
                int row = m0 + wid * 16 + l4 * 4 + j;
                if (row < mend) {
                    int orig = perm[row];
                    out[orig] = 1.f / (1.f + expf(-(part[j] + b2)));
                }
            }
        }
        __builtin_amdgcn_s_barrier();
    }
}

// ---------------------------------------------------------------------------
extern "C" void kernel_launch(void* const* d_in, const int* in_sizes, int n_in,
                              void* d_out, int out_size, void* d_ws, size_t ws_size,
                              hipStream_t stream) {
    (void)in_sizes; (void)n_in; (void)out_size;
    if (ws_size < WS_NEED) return;   // visible clean-fail if scratch too small

    const float* x    = (const float*)d_in[0];
    const int*   bt   = (const int*)d_in[1];
    const float* ws1W = (const float*)d_in[2];
    const float* ws1b = (const float*)d_in[3];
    const float* wt1W = (const float*)d_in[4];
    const float* wt1b = (const float*)d_in[5];
    const float* ws2W = (const float*)d_in[6];
    const float* ws2b = (const float*)d_in[7];
    const float* wt2W = (const float*)d_in[8];
    const float* wt2b = (const float*)d_in[9];
    const float* h1W  = (const float*)d_in[10];
    const float* h1b  = (const float*)d_in[11];
    const float* h2W  = (const float*)d_in[12];
    const float* h2b  = (const float*)d_in[13];

    char* ws = (char*)d_ws;
    int* perm = (int*)(ws + OFF_PERM);
    int* seg  = (int*)(ws + OFF_SEG);
    unsigned short* wb = (unsigned short*)(ws + OFF_W);
    unsigned short* xp = (unsigned short*)(ws + OFF_XP);
    unsigned short* a0 = (unsigned short*)(ws + OFF_A0);
    unsigned short* a1 = (unsigned short*)(ws + OFF_A1);
    float* outp = (float*)d_out;

    perm_kernel<<<1, 256, 0, stream>>>(bt, perm, seg);
    transpose_cvt<<<dim3(16, 16, 24), 256, 0, stream>>>(ws1W, wt1W, ws2W, wt2W, h1W, wb);

    void* args[] = {
        (void*)&x, (void*)&perm, (void*)&seg, (void*)&wb,
        (void*)&ws1b, (void*)&wt1b, (void*)&ws2b, (void*)&wt2b,
        (void*)&h1b, (void*)&h2W, (void*)&h2b,
        (void*)&xp, (void*)&a0, (void*)&a1, (void*)&outp
    };
    hipLaunchCooperativeKernel((const void*)fused_mlp, dim3(512), dim3(256),
                               args, 0, stream);
}

// Round 7
// 354.988 us; speedup vs baseline: 3.7072x; 3.7072x over previous
//
#include <hip/hip_runtime.h>

// ---------------------------------------------------------------------------
// multitask MLP, MI355X bf16 MFMA — round 7
// r6 -> r7: fusion refuted (grid.sync ~100us each on 8 XCDs; counters showed
// 98% stall, MfmaUtil 1.2%). Revert to multi-kernel. NEW GEMM STRUCTURE:
// one wave per block, wave-tile = full 64x64 (acc[4][4]) -> ZERO barriers,
// self-paced on counted vmcnt(16); 32 MFMA : 16 ds_read_b128 per k-step.
// 3 LDS buffers, 2-deep prefetch, XOR slot-swizzle (verified conflict-free).
// ---------------------------------------------------------------------------

typedef __attribute__((ext_vector_type(4))) float f32x4;
typedef __attribute__((ext_vector_type(8))) __bf16 bf16x8;
typedef __attribute__((ext_vector_type(4))) unsigned short u16x4;

#define AS1 __attribute__((address_space(1)))
#define AS3 __attribute__((address_space(3)))

static constexpr int B_  = 2048;
static constexpr int D_  = 1024;
static constexpr int T_  = 4;
static constexpr int H_  = 64;
static constexpr int MP_ = 2112;                    // B_ padded by 64 for tile overrun
static constexpr size_t MSZ = (size_t)D_ * D_;      // elems per DxD matrix (1M)

// ws layout (bytes)
static constexpr size_t OFF_PERM = 0;                         // 2048 int
static constexpr size_t OFF_SEG  = 8192;                      // 8 int
static constexpr size_t OFF_W    = 16384;                     // bf16 transposed weights
//   matrices 0..1: ws1 l0,l1 | 2..9: wt1 (t*2+l) | 10..11: ws2 | 12..19: wt2 (t*2+l)
//   then h1t: 4 * [64][1024]
static constexpr size_t H1T_ELEM_OFF = 20 * MSZ;
static constexpr size_t W_ELEMS  = 20 * MSZ + (size_t)T_ * H_ * D_;
static constexpr size_t OFF_XP   = OFF_W + W_ELEMS * 2;
static constexpr size_t ACT_BYTES = (size_t)MP_ * D_ * 2;
static constexpr size_t OFF_A0   = OFF_XP + ACT_BYTES;
static constexpr size_t OFF_A1   = OFF_A0 + ACT_BYTES;
static constexpr size_t WS_NEED  = OFF_A1 + ACT_BYTES;        // ~53 MiB

static __device__ __forceinline__ unsigned short f2bf(float f) {
    union { float f; unsigned int u; } v; v.f = f;
    unsigned int r = v.u + 0x7fffu + ((v.u >> 16) & 1u);      // RNE
    return (unsigned short)(r >> 16);
}

// ---------------------------------------------------------------------------
// 1) per-task segments + permutation (1 block)
// ---------------------------------------------------------------------------
__global__ void perm_kernel(const int* __restrict__ btask,
                            int* __restrict__ perm, int* __restrict__ seg) {
    __shared__ int cnt[T_], cur[T_];
    int tid = threadIdx.x;
    if (tid < T_) cnt[tid] = 0;
    __syncthreads();
    for (int i = tid; i < B_; i += 256) atomicAdd(&cnt[btask[i]], 1);
    __syncthreads();
    if (tid == 0) {
        int s = 0;
        for (int t = 0; t < T_; ++t) {
            seg[t] = s; seg[T_ + t] = cnt[t]; cur[t] = s; s += cnt[t];
        }
    }
    __syncthreads();
    for (int i = tid; i < B_; i += 256) {
        int t = btask[i];
        int p = atomicAdd(&cur[t], 1);
        perm[p] = i;
    }
}

// ---------------------------------------------------------------------------
// 2) fp32 -> bf16 transpose of all weight matrices.  z: matrix id 0..23.
// ---------------------------------------------------------------------------
__global__ __launch_bounds__(256)
void transpose_cvt(const float* __restrict__ ws1, const float* __restrict__ wt1,
                   const float* __restrict__ ws2, const float* __restrict__ wt2,
                   const float* __restrict__ h1, unsigned short* __restrict__ wb) {
    int z = blockIdx.z;
    const float* src; unsigned short* dst; int C = D_;
    if (z < 2)       { src = ws1 + (size_t)z * MSZ;        dst = wb + (size_t)z * MSZ; }
    else if (z < 10) { src = wt1 + (size_t)(z - 2) * MSZ;  dst = wb + (size_t)z * MSZ; }
    else if (z < 12) { src = ws2 + (size_t)(z - 10) * MSZ; dst = wb + (size_t)z * MSZ; }
    else if (z < 20) { src = wt2 + (size_t)(z - 12) * MSZ; dst = wb + (size_t)z * MSZ; }
    else { src = h1 + (size_t)(z - 20) * (D_ * H_);
           dst = wb + H1T_ELEM_OFF + (size_t)(z - 20) * (D_ * H_); C = H_; }
    int r0 = blockIdx.y * 64, c0 = blockIdx.x * 64;
    if (c0 >= C) return;
    __shared__ float tile[64][65];
    int tid = threadIdx.x;
#pragma unroll
    for (int i = 0; i < 4; ++i) {
        int idx = i * 256 + tid;
        int fr = idx >> 4, fc = (idx & 15) << 2;
        float4 v = *(const float4*)(src + (size_t)(r0 + fr) * C + c0 + fc);
        tile[fr][fc] = v.x; tile[fr][fc + 1] = v.y; tile[fr][fc + 2] = v.z; tile[fr][fc + 3] = v.w;
    }
    __syncthreads();
#pragma unroll
    for (int i = 0; i < 4; ++i) {
        int idx = i * 256 + tid;
        int orow = idx >> 4, ocb = (idx & 15) << 2;
        u16x4 o = { f2bf(tile[ocb][orow]),     f2bf(tile[ocb + 1][orow]),
                    f2bf(tile[ocb + 2][orow]), f2bf(tile[ocb + 3][orow]) };
        *(u16x4*)(dst + (size_t)(c0 + orow) * D_ + r0 + ocb) = o;
    }
}

// ---------------------------------------------------------------------------
// 3) gather x into permuted order, convert to bf16.  1 block = 1 row.
// ---------------------------------------------------------------------------
__global__ void gather_x(const float* __restrict__ x, const int* __restrict__ perm,
                         unsigned short* __restrict__ xp) {
    int pos = blockIdx.x;
    int src = perm[pos];
    int t = threadIdx.x;                       // 256 threads * 4 floats
    float4 v = *((const float4*)(x + (size_t)src * D_) + t);
    u16x4 o = { f2bf(v.x), f2bf(v.y), f2bf(v.z), f2bf(v.w) };
    *((u16x4*)(xp + (size_t)pos * D_) + t) = o;
}

// ---------------------------------------------------------------------------
// 4) GEMM pass: ONE WAVE per block, tile 64x64, acc[4][4] (whole tile).
//    No barriers. 3 LDS buffers; per k-step 16 global_load_lds (8 A + 8 B),
//    2-deep prefetch, steady wait vmcnt(16) (= stage t landed, t+1/t+2 in
//    flight).  Per k-step: 16 ds_read_b128 -> 32 MFMA (2:1 ILP).
//    XOR slot-swizzle: LDS dest linear; global source slot (L&7)^(L>>3);
//    ds_read slot (kk*4+l4)^(row&7).
// ---------------------------------------------------------------------------
template<bool RELU, bool TASK>
__global__ __launch_bounds__(64)
void gemm_pass(const unsigned short* __restrict__ A, const unsigned short* __restrict__ W,
               const float* __restrict__ bias, unsigned short* __restrict__ Out,
               const int* __restrict__ seg, size_t wstride, size_t bstride) {
    __shared__ unsigned short lA[3][64 * 64];      // 3 x 8 KB
    __shared__ unsigned short lB[3][64 * 64];      // 3 x 8 KB  (48 KB)
    int m0, mend, t = 0;
    if (TASK) {
        t = blockIdx.y >> 5;
        int mt = blockIdx.y & 31;
        int s = seg[t], c = seg[4 + t];
        m0 = s + mt * 64; mend = s + c;
        if (m0 >= mend) return;
    } else { m0 = blockIdx.y * 64; mend = B_; }
    const unsigned short* Wt = W + (size_t)t * wstride;
    const float* bs = bias + (size_t)t * bstride;
    const int n0 = blockIdx.x * 64;

    const int lane = threadIdx.x & 63;
    const int l15 = lane & 15, l4 = lane >> 4;
    const int srow = lane >> 3;                    // 0..7 within staging chunk
    const int sslot = ((lane & 7) ^ srow) * 16;    // pre-swizzled source slot (bytes)

    f32x4 acc[4][4] = {};

    const char* Abase = (const char*)(A + (size_t)m0 * D_) + (size_t)srow * (D_ * 2) + sslot;
    const char* Bbase = (const char*)(Wt + (size_t)n0 * D_) + (size_t)srow * (D_ * 2) + sslot;

    auto stage = [&](int kt, int buf) {
        const size_t k0b = (size_t)kt * 128;       // 64 elems * 2B
#pragma unroll
        for (int c = 0; c < 8; ++c) {              // A: 8 chunks of 8 rows x 128B
            const char* sa = Abase + (size_t)c * (8 * D_ * 2) + k0b;
            __builtin_amdgcn_global_load_lds((AS1 void*)sa,
                (AS3 void*)(&lA[buf][0] + (size_t)c * 512), 16, 0, 0);
        }
#pragma unroll
        for (int c = 0; c < 8; ++c) {              // B: 8 chunks
            const char* sb = Bbase + (size_t)c * (8 * D_ * 2) + k0b;
            __builtin_amdgcn_global_load_lds((AS1 void*)sb,
                (AS3 void*)(&lB[buf][0] + (size_t)c * 512), 16, 0, 0);
        }
    };

    auto compute = [&](int buf) {
        const unsigned short* bA = &lA[buf][0];
        const unsigned short* bB = &lB[buf][0];
#pragma unroll
        for (int kk = 0; kk < 2; ++kk) {
            const int swz = (((kk * 4) + l4) ^ (l15 & 7)) * 8;   // swizzled k-offset (elems)
            bf16x8 af[4], bfr[4];
#pragma unroll
            for (int m = 0; m < 4; ++m)
                af[m] = *(const bf16x8*)(bA + (m * 16 + l15) * 64 + swz);
#pragma unroll
            for (int n = 0; n < 4; ++n)
                bfr[n] = *(const bf16x8*)(bB + (n * 16 + l15) * 64 + swz);
#pragma unroll
            for (int m = 0; m < 4; ++m)
#pragma unroll
                for (int n = 0; n < 4; ++n)
                    acc[m][n] = __builtin_amdgcn_mfma_f32_16x16x32_bf16(af[m], bfr[n], acc[m][n], 0, 0, 0);
        }
    };

    stage(0, 0);
    stage(1, 1);
    int bc = 0, bn2 = 2;
#pragma unroll 1
    for (int kt = 0; kt < 14; ++kt) {              // 16 k-steps, 2 peeled
        asm volatile("s_waitcnt vmcnt(16)" ::: "memory");   // stage(kt) landed
        stage(kt + 2, bn2);
        compute(bc);
        bc  = (bc  == 2) ? 0 : bc  + 1;
        bn2 = (bn2 == 2) ? 0 : bn2 + 1;
    }
    asm volatile("s_waitcnt vmcnt(16)" ::: "memory");
    compute(bc);
    bc = (bc == 2) ? 0 : bc + 1;
    asm volatile("s_waitcnt vmcnt(0)" ::: "memory");
    compute(bc);

    // epilogue: C/D layout col=lane&15, row=(lane>>4)*4+j  [guide §3, m89-verified]
#pragma unroll
    for (int n = 0; n < 4; ++n) {
        int col = n0 + n * 16 + l15;
        float bv = bs[col];
#pragma unroll
        for (int m = 0; m < 4; ++m) {
            int rbase = m0 + m * 16 + l4 * 4;
#pragma unroll
            for (int j = 0; j < 4; ++j) {
                int row = rbase + j;
                if (!TASK || row < mend) {
                    float v = acc[m][n][j] + bv;
                    if (RELU) v = fmaxf(v, 0.f);
                    Out[(size_t)row * D_ + col] = f2bf(v);
                }
            }
        }
    }
}

// ---------------------------------------------------------------------------
// 5) head (r5-proven): 4 waves, pipeline vmcnt(4): r = A @ H1t[t] + h1_b
//    (no relu), logit = r . h2_W[t] + h2_b[t], out[orig] = sigmoid(logit).
// ---------------------------------------------------------------------------
__global__ __launch_bounds__(256)
void head_pass(const unsigned short* __restrict__ A, const unsigned short* __restrict__ H1t,
               const float* __restrict__ h1b, const float* __restrict__ h2w,
               const float* __restrict__ h2b, const int* __restrict__ seg,
               const int* __restrict__ perm, float* __restrict__ out) {
    __shared__ unsigned short lA[3][64 * 64];
    __shared__ unsigned short lB[3][64 * 64];      // 48 KB total
    int t = blockIdx.x >> 5, mt = blockIdx.x & 31;
    int s = seg[t], c = seg[4 + t];
    int m0 = s + mt * 64, mend = s + c;
    if (m0 >= mend) return;
    const unsigned short* Ht = H1t + (size_t)t * (H_ * D_);
    const int tid = threadIdx.x, wid = tid >> 6, lane = tid & 63;
    const int l15 = lane & 15, l4 = lane >> 4;
    const int srow = lane >> 3;
    const int sslot = ((lane & 7) ^ srow) * 16;
    f32x4 acc[4] = {};

    auto stage = [&](int kt, int buf) {
        const int k0 = kt * 64;
#pragma unroll
        for (int i = 0; i < 2; ++i) {
            int chunk = wid * 2 + i;
            int row = chunk * 8 + srow;
            const char* sa = (const char*)(A + (size_t)(m0 + row) * D_ + k0) + sslot;
            __builtin_amdgcn_global_load_lds((AS1 void*)sa,
                (AS3 void*)(&lA[buf][0] + (size_t)chunk * 512), 16, 0, 0);
            const char* sb = (const char*)(Ht + (size_t)row * D_ + k0) + sslot;
            __builtin_amdgcn_global_load_lds((AS1 void*)sb,
                (AS3 void*)(&lB[buf][0] + (size_t)chunk * 512), 16, 0, 0);
        }
    };
    auto compute = [&](int buf) {
#pragma unroll
        for (int kk = 0; kk < 2; ++kk) {
            const int swz = (((kk * 4) + l4) ^ (l15 & 7)) * 8;
            bf16x8 af = *(const bf16x8*)(&lA[buf][0] + (wid * 16 + l15) * 64 + swz);
#pragma unroll
            for (int n = 0; n < 4; ++n) {
                bf16x8 bfr = *(const bf16x8*)(&lB[buf][0] + (n * 16 + l15) * 64 + swz);
                acc[n] = __builtin_amdgcn_mfma_f32_16x16x32_bf16(af, bfr, acc[n], 0, 0, 0);
            }
        }
    };

    stage(0, 0);
    stage(1, 1);
    int bc = 0, bn2 = 2;
#pragma unroll 1
    for (int kt = 0; kt < 14; ++kt) {
        asm volatile("s_waitcnt vmcnt(4)" ::: "memory");
        __builtin_amdgcn_s_barrier();
        stage(kt + 2, bn2);
        compute(bc);
        bc  = (bc  == 2) ? 0 : bc  + 1;
        bn2 = (bn2 == 2) ? 0 : bn2 + 1;
    }
    asm volatile("s_waitcnt vmcnt(4)" ::: "memory");
    __builtin_amdgcn_s_barrier();
    compute(bc);
    bc = (bc == 2) ? 0 : bc + 1;
    asm volatile("s_waitcnt vmcnt(0)" ::: "memory");
    __builtin_amdgcn_s_barrier();
    compute(bc);

    float part[4] = {0.f, 0.f, 0.f, 0.f};
#pragma unroll
    for (int n = 0; n < 4; ++n) {
        int col = n * 16 + l15;
        float b1 = h1b[t * H_ + col];
        float w2 = h2w[t * H_ + col];
#pragma unroll
        for (int j = 0; j < 4; ++j) part[j] += (acc[n][j] + b1) * w2;
    }
#pragma unroll
    for (int msk = 1; msk < 16; msk <<= 1)
#pragma unroll
        for (int j = 0; j < 4; ++j) part[j] += __shfl_xor(part[j], msk);
    if (l15 == 0) {
        float b2 = h2b[t];
#pragma unroll
        for (int j = 0; j < 4; ++j) {
            int row = m0 + wid * 16 + l4 * 4 + j;
            if (row < mend) {
                int orig = perm[row];
                out[orig] = 1.f / (1.f + expf(-(part[j] + b2)));
            }
        }
    }
}

// ---------------------------------------------------------------------------
extern "C" void kernel_launch(void* const* d_in, const int* in_sizes, int n_in,
                              void* d_out, int out_size, void* d_ws, size_t ws_size,
                              hipStream_t stream) {
    (void)in_sizes; (void)n_in; (void)out_size;
    if (ws_size < WS_NEED) return;   // visible clean-fail if scratch too small

    const float* x    = (const float*)d_in[0];
    const int*   bt   = (const int*)d_in[1];
    const float* ws1W = (const float*)d_in[2];
    const float* ws1b = (const float*)d_in[3];
    const float* wt1W = (const float*)d_in[4];
    const float* wt1b = (const float*)d_in[5];
    const float* ws2W = (const float*)d_in[6];
    const float* ws2b = (const float*)d_in[7];
    const float* wt2W = (const float*)d_in[8];
    const float* wt2b = (const float*)d_in[9];
    const float* h1W  = (const float*)d_in[10];
    const float* h1b  = (const float*)d_in[11];
    const float* h2W  = (const float*)d_in[12];
    const float* h2b  = (const float*)d_in[13];

    char* ws = (char*)d_ws;
    int* perm = (int*)(ws + OFF_PERM);
    int* seg  = (int*)(ws + OFF_SEG);
    unsigned short* wb = (unsigned short*)(ws + OFF_W);
    unsigned short* xp = (unsigned short*)(ws + OFF_XP);
    unsigned short* a0 = (unsigned short*)(ws + OFF_A0);
    unsigned short* a1 = (unsigned short*)(ws + OFF_A1);

    perm_kernel<<<1, 256, 0, stream>>>(bt, perm, seg);
    transpose_cvt<<<dim3(16, 16, 24), 256, 0, stream>>>(ws1W, wt1W, ws2W, wt2W, h1W, wb);
    gather_x<<<B_, 256, 0, stream>>>(x, perm, xp);

    dim3 gs(16, 32), gt(16, 128);                  // 64-thread blocks now
    // shared1: lin, then relu->lin  (relu folded into producer epilogue)
    gemm_pass<true,  false><<<gs, 64, 0, stream>>>(xp, wb + 0 * MSZ,  ws1b + 0,  a0, seg, 0, 0);
    gemm_pass<true,  false><<<gs, 64, 0, stream>>>(a0, wb + 1 * MSZ,  ws1b + D_, a1, seg, 0, 0);
    // task1: (relu->lin)x2 ; second layer output feeds shared2 RAW -> no relu
    gemm_pass<true,  true ><<<gt, 64, 0, stream>>>(a1, wb + 2 * MSZ,  wt1b + 0,  a0, seg, 2 * MSZ, 2 * D_);
    gemm_pass<false, true ><<<gt, 64, 0, stream>>>(a0, wb + 3 * MSZ,  wt1b + D_, a1, seg, 2 * MSZ, 2 * D_);
    // shared2
    gemm_pass<true,  false><<<gs, 64, 0, stream>>>(a1, wb + 10 * MSZ, ws2b + 0,  a0, seg, 0, 0);
    gemm_pass<true,  false><<<gs, 64, 0, stream>>>(a0, wb + 11 * MSZ, ws2b + D_, a1, seg, 0, 0);
    // task2 body
    gemm_pass<true,  true ><<<gt, 64, 0, stream>>>(a1, wb + 12 * MSZ, wt2b + 0,  a0, seg, 2 * MSZ, 2 * D_);
    gemm_pass<true,  true ><<<gt, 64, 0, stream>>>(a0, wb + 13 * MSZ, wt2b + D_, a1, seg, 2 * MSZ, 2 * D_);
    // head: D->64 (+bias, no relu), dot h2, sigmoid, scatter
    head_pass<<<dim3(128), 256, 0, stream>>>(a1, wb + H1T_ELEM_OFF, h1b, h2W, h2b, seg, perm, (float*)d_out);
}

// Round 9
// 302.075 us; speedup vs baseline: 4.3566x; 1.1752x over previous
//
#include <hip/hip_runtime.h>

// ---------------------------------------------------------------------------
// multitask MLP, MI355X bf16 MFMA — round 8 (resubmit; r8 bench lost to GPU
// acquisition timeout, no data)
// r5 -> r8 (r7 single-wave refuted; r5 structure restored):
//  (1) XCD-affine tile mapping: bid%8 == m_panel%8 for every GEMM layer and
//      for gather_x -> the 16 n-tiles sharing an A-panel AND the producer of
//      that panel (previous layer) live on ONE XCD => activation staging
//      becomes local-L2 instead of cross-XCD snoops.  (bid->XCD = bid%8.)
//  (2) 3-deep prefetch: 4 LDS buffers, steady s_waitcnt vmcnt(8) -> ~3 k-steps
//      (~900+ cy) of latency cover for the L3-served weight panels.
// Everything else identical to r5 (64x64x64 tile, 4 waves 2x2, XOR swizzle,
// one raw s_barrier per k-step).
// ---------------------------------------------------------------------------

typedef __attribute__((ext_vector_type(4))) float f32x4;
typedef __attribute__((ext_vector_type(8))) __bf16 bf16x8;
typedef __attribute__((ext_vector_type(4))) unsigned short u16x4;

#define AS1 __attribute__((address_space(1)))
#define AS3 __attribute__((address_space(3)))

static constexpr int B_  = 2048;
static constexpr int D_  = 1024;
static constexpr int T_  = 4;
static constexpr int H_  = 64;
static constexpr int MP_ = 2112;                    // B_ padded by 64 for tile overrun
static constexpr size_t MSZ = (size_t)D_ * D_;      // elems per DxD matrix (1M)

// ws layout (bytes)
static constexpr size_t OFF_PERM = 0;                         // 2048 int
static constexpr size_t OFF_SEG  = 8192;                      // 8 int
static constexpr size_t OFF_W    = 16384;                     // bf16 transposed weights
//   matrices 0..1: ws1 l0,l1 | 2..9: wt1 (t*2+l) | 10..11: ws2 | 12..19: wt2 (t*2+l)
//   then h1t: 4 * [64][1024]
static constexpr size_t H1T_ELEM_OFF = 20 * MSZ;
static constexpr size_t W_ELEMS  = 20 * MSZ + (size_t)T_ * H_ * D_;
static constexpr size_t OFF_XP   = OFF_W + W_ELEMS * 2;
static constexpr size_t ACT_BYTES = (size_t)MP_ * D_ * 2;
static constexpr size_t OFF_A0   = OFF_XP + ACT_BYTES;
static constexpr size_t OFF_A1   = OFF_A0 + ACT_BYTES;
static constexpr size_t WS_NEED  = OFF_A1 + ACT_BYTES;        // ~53 MiB

static __device__ __forceinline__ unsigned short f2bf(float f) {
    union { float f; unsigned int u; } v; v.f = f;
    unsigned int r = v.u + 0x7fffu + ((v.u >> 16) & 1u);      // RNE
    return (unsigned short)(r >> 16);
}

// ---------------------------------------------------------------------------
// 1) per-task segments + permutation (1 block)
// ---------------------------------------------------------------------------
__global__ void perm_kernel(const int* __restrict__ btask,
                            int* __restrict__ perm, int* __restrict__ seg) {
    __shared__ int cnt[T_], cur[T_];
    int tid = threadIdx.x;
    if (tid < T_) cnt[tid] = 0;
    __syncthreads();
    for (int i = tid; i < B_; i += 256) atomicAdd(&cnt[btask[i]], 1);
    __syncthreads();
    if (tid == 0) {
        int s = 0;
        for (int t = 0; t < T_; ++t) {
            seg[t] = s; seg[T_ + t] = cnt[t]; cur[t] = s; s += cnt[t];
        }
    }
    __syncthreads();
    for (int i = tid; i < B_; i += 256) {
        int t = btask[i];
        int p = atomicAdd(&cur[t], 1);
        perm[p] = i;
    }
}

// ---------------------------------------------------------------------------
// 2) fp32 -> bf16 transpose of all weight matrices.  z: matrix id 0..23.
// ---------------------------------------------------------------------------
__global__ __launch_bounds__(256)
void transpose_cvt(const float* __restrict__ ws1, const float* __restrict__ wt1,
                   const float* __restrict__ ws2, const float* __restrict__ wt2,
                   const float* __restrict__ h1, unsigned short* __restrict__ wb) {
    int z = blockIdx.z;
    const float* src; unsigned short* dst; int C = D_;
    if (z < 2)       { src = ws1 + (size_t)z * MSZ;        dst = wb + (size_t)z * MSZ; }
    else if (z < 10) { src = wt1 + (size_t)(z - 2) * MSZ;  dst = wb + (size_t)z * MSZ; }
    else if (z < 12) { src = ws2 + (size_t)(z - 10) * MSZ; dst = wb + (size_t)z * MSZ; }
    else if (z < 20) { src = wt2 + (size_t)(z - 12) * MSZ; dst = wb + (size_t)z * MSZ; }
    else { src = h1 + (size_t)(z - 20) * (D_ * H_);
           dst = wb + H1T_ELEM_OFF + (size_t)(z - 20) * (D_ * H_); C = H_; }
    int r0 = blockIdx.y * 64, c0 = blockIdx.x * 64;
    if (c0 >= C) return;
    __shared__ float tile[64][65];
    int tid = threadIdx.x;
#pragma unroll
    for (int i = 0; i < 4; ++i) {
        int idx = i * 256 + tid;
        int fr = idx >> 4, fc = (idx & 15) << 2;
        float4 v = *(const float4*)(src + (size_t)(r0 + fr) * C + c0 + fc);
        tile[fr][fc] = v.x; tile[fr][fc + 1] = v.y; tile[fr][fc + 2] = v.z; tile[fr][fc + 3] = v.w;
    }
    __syncthreads();
#pragma unroll
    for (int i = 0; i < 4; ++i) {
        int idx = i * 256 + tid;
        int orow = idx >> 4, ocb = (idx & 15) << 2;
        u16x4 o = { f2bf(tile[ocb][orow]),     f2bf(tile[ocb + 1][orow]),
                    f2bf(tile[ocb + 2][orow]), f2bf(tile[ocb + 3][orow]) };
        *(u16x4*)(dst + (size_t)(c0 + orow) * D_ + r0 + ocb) = o;
    }
}

// ---------------------------------------------------------------------------
// 3) gather x, XCD-affine: block bid handles row pos with (pos>>6)%8 == bid%8,
//    so the first GEMM's A-panel readers (also on XCD pos>>6 %8) hit local L2.
// ---------------------------------------------------------------------------
__global__ void gather_x(const float* __restrict__ x, const int* __restrict__ perm,
                         unsigned short* __restrict__ xp) {
    int bid = blockIdx.x;                      // 2048 blocks
    int panel = (bid & 7) + (((bid >> 3) & 3) << 3);   // 0..31, panel%8 == bid%8
    int pos = (panel << 6) + (bid >> 5);
    int src = perm[pos];
    int t = threadIdx.x;                       // 256 threads * 4 floats
    float4 v = *((const float4*)(x + (size_t)src * D_) + t);
    u16x4 o = { f2bf(v.x), f2bf(v.y), f2bf(v.z), f2bf(v.w) };
    *((u16x4*)(xp + (size_t)pos * D_) + t) = o;
}

// ---------------------------------------------------------------------------
// 4) GEMM pass: BM=64 BN=64 BK=64, 4 waves (2x2), XOR slot-swizzle,
//    XCD-affine bid->(m_panel,n) mapping, 4 LDS buffers / 3-deep prefetch,
//    steady vmcnt(8), one raw s_barrier per k-step.
//    iter t: vmcnt(8) [stage(t) landed] -> barrier -> stage(t+3) -> compute(t)
// ---------------------------------------------------------------------------
template<bool RELU, bool TASK>
__global__ __launch_bounds__(256, 2)
void gemm_pass(const unsigned short* __restrict__ A, const unsigned short* __restrict__ W,
               const float* __restrict__ bias, unsigned short* __restrict__ Out,
               const int* __restrict__ seg, size_t wstride, size_t bstride) {
    __shared__ unsigned short lA[4][4096];         // 4 x 8 KB
    __shared__ unsigned short lB[4][4096];         // 4 x 8 KB  (64 KB total)
    const int bid = blockIdx.x;
    const int x = bid & 7;                         // == XCD id (bid%8 round-robin)
    int m0, mend, n0, t = 0;
    if (TASK) {                                    // 2048 blocks
        int q = bid >> 3;                          // 0..255
        t = q >> 6;
        int qq = q & 63;
        n0 = (qq & 15) << 6;
        int j = qq >> 4;                           // 0..3
        int s = seg[t], c = seg[4 + t];
        int bp = s >> 6;
        int mt = ((x - bp) & 7) + (j << 3);        // (s+mt*64)>>6 == bp+mt ≡ x (mod 8)
        m0 = s + (mt << 6);
        mend = s + c;
        if (m0 >= mend) return;
    } else {                                       // 512 blocks
        int q = bid >> 3;                          // 0..63
        int mp = x + ((q >> 4) << 3);              // m_panel, mp%8 == x
        n0 = (q & 15) << 6;
        m0 = mp << 6;
        mend = B_;
    }
    const unsigned short* Wt = W + (size_t)t * wstride;
    const float* bs = bias + (size_t)t * bstride;

    const int tid = threadIdx.x, wid = tid >> 6, lane = tid & 63;
    const int wm = wid >> 1, wn = wid & 1;
    const int l15 = lane & 15, l4 = lane >> 4;
    const int srow = lane >> 3;                    // 0..7 within staging chunk
    const int sslot = ((lane & 7) ^ srow) * 16;    // pre-swizzled source slot (bytes)

    f32x4 acc[2][2] = {};

    auto stage = [&](int kt, int buf) {
        const int k0 = kt * 64;
#pragma unroll
        for (int i = 0; i < 2; ++i) {              // 2 A-chunks + 2 B-chunks / wave
            int chunk = wid * 2 + i;
            int row = chunk * 8 + srow;
            const char* sa = (const char*)(A + (size_t)(m0 + row) * D_ + k0) + sslot;
            __builtin_amdgcn_global_load_lds((AS1 void*)sa,
                (AS3 void*)(&lA[buf][0] + (size_t)chunk * 512), 16, 0, 0);
            const char* sb = (const char*)(Wt + (size_t)(n0 + row) * D_ + k0) + sslot;
            __builtin_amdgcn_global_load_lds((AS1 void*)sb,
                (AS3 void*)(&lB[buf][0] + (size_t)chunk * 512), 16, 0, 0);
        }
    };

    auto compute = [&](int buf) {
        const unsigned short* bA = &lA[buf][0];
        const unsigned short* bB = &lB[buf][0];
#pragma unroll
        for (int kk = 0; kk < 2; ++kk) {
            const int swz = (((kk * 4) + l4) ^ (l15 & 7)) * 8;   // swizzled k-offset (elems)
            bf16x8 af[2], bfr[2];
#pragma unroll
            for (int m = 0; m < 2; ++m)
                af[m] = *(const bf16x8*)(bA + (wm * 32 + m * 16 + l15) * 64 + swz);
#pragma unroll
            for (int n = 0; n < 2; ++n)
                bfr[n] = *(const bf16x8*)(bB + (wn * 32 + n * 16 + l15) * 64 + swz);
#pragma unroll
            for (int m = 0; m < 2; ++m)
#pragma unroll
                for (int n = 0; n < 2; ++n)
                    acc[m][n] = __builtin_amdgcn_mfma_f32_16x16x32_bf16(af[m], bfr[n], acc[m][n], 0, 0, 0);
        }
    };

    stage(0, 0);
    stage(1, 1);
    stage(2, 2);
    int bc = 0, bn3 = 3;
#pragma unroll 1
    for (int kt = 0; kt < 13; ++kt) {              // 16 k-steps, 3 peeled
        asm volatile("s_waitcnt vmcnt(8)" ::: "memory");   // stage(kt) landed
        __builtin_amdgcn_s_barrier();
        stage(kt + 3, bn3);
        compute(bc);
        bc = (bc + 1) & 3; bn3 = (bn3 + 1) & 3;
    }
    asm volatile("s_waitcnt vmcnt(8)" ::: "memory");
    __builtin_amdgcn_s_barrier();
    compute(bc); bc = (bc + 1) & 3;
    asm volatile("s_waitcnt vmcnt(4)" ::: "memory");
    __builtin_amdgcn_s_barrier();
    compute(bc); bc = (bc + 1) & 3;
    asm volatile("s_waitcnt vmcnt(0)" ::: "memory");
    __builtin_amdgcn_s_barrier();
    compute(bc);

    // epilogue: C/D layout col=lane&15, row=(lane>>4)*4+j  [guide §3, m89-verified]
#pragma unroll
    for (int n = 0; n < 2; ++n) {
        int col = n0 + wn * 32 + n * 16 + l15;
        float bv = bs[col];
#pragma unroll
        for (int m = 0; m < 2; ++m) {
            int rbase = m0 + wm * 32 + m * 16 + l4 * 4;
#pragma unroll
            for (int j = 0; j < 4; ++j) {
                int row = rbase + j;
                if (!TASK || row < mend) {
                    float v = acc[m][n][j] + bv;
                    if (RELU) v = fmaxf(v, 0.f);
                    Out[(size_t)row * D_ + col] = f2bf(v);
                }
            }
        }
    }
}

// ---------------------------------------------------------------------------
// 5) head (r5-proven): 4 waves, 3-buf pipeline vmcnt(4): r = A @ H1t[t] + h1_b
//    (no relu), logit = r . h2_W[t] + h2_b[t], out[orig] = sigmoid(logit).
// ---------------------------------------------------------------------------
__global__ __launch_bounds__(256)
void head_pass(const unsigned short* __restrict__ A, const unsigned short* __restrict__ H1t,
               const float* __restrict__ h1b, const float* __restrict__ h2w,
               const float* __restrict__ h2b, const int* __restrict__ seg,
               const int* __restrict__ perm, float* __restrict__ out) {
    __shared__ unsigned short lA[3][4096];
    __shared__ unsigned short lB[3][4096];         // 48 KB total
    int t = blockIdx.x >> 5, mt = blockIdx.x & 31;
    int s = seg[t], c = seg[4 + t];
    int m0 = s + mt * 64, mend = s + c;
    if (m0 >= mend) return;
    const unsigned short* Ht = H1t + (size_t)t * (H_ * D_);
    const int tid = threadIdx.x, wid = tid >> 6, lane = tid & 63;
    const int l15 = lane & 15, l4 = lane >> 4;
    const int srow = lane >> 3;
    const int sslot = ((lane & 7) ^ srow) * 16;
    f32x4 acc[4] = {};

    auto stage = [&](int kt, int buf) {
        const int k0 = kt * 64;
#pragma unroll
        for (int i = 0; i < 2; ++i) {
            int chunk = wid * 2 + i;
            int row = chunk * 8 + srow;
            const char* sa = (const char*)(A + (size_t)(m0 + row) * D_ + k0) + sslot;
            __builtin_amdgcn_global_load_lds((AS1 void*)sa,
                (AS3 void*)(&lA[buf][0] + (size_t)chunk * 512), 16, 0, 0);
            const char* sb = (const char*)(Ht + (size_t)row * D_ + k0) + sslot;
            __builtin_amdgcn_global_load_lds((AS1 void*)sb,
                (AS3 void*)(&lB[buf][0] + (size_t)chunk * 512), 16, 0, 0);
        }
    };
    auto compute = [&](int buf) {
#pragma unroll
        for (int kk = 0; kk < 2; ++kk) {
            const int swz = (((kk * 4) + l4) ^ (l15 & 7)) * 8;
            bf16x8 af = *(const bf16x8*)(&lA[buf][0] + (wid * 16 + l15) * 64 + swz);
#pragma unroll
            for (int n = 0; n < 4; ++n) {
                bf16x8 bfr = *(const bf16x8*)(&lB[buf][0] + (n * 16 + l15) * 64 + swz);
                acc[n] = __builtin_amdgcn_mfma_f32_16x16x32_bf16(af, bfr, acc[n], 0, 0, 0);
            }
        }
    };

    stage(0, 0);
    stage(1, 1);
    int bc = 0, bn2 = 2;
#pragma unroll 1
    for (int kt = 0; kt < 14; ++kt) {
        asm volatile("s_waitcnt vmcnt(4)" ::: "memory");
        __builtin_amdgcn_s_barrier();
        stage(kt + 2, bn2);
        compute(bc);
        bc  = (bc  == 2) ? 0 : bc  + 1;
        bn2 = (bn2 == 2) ? 0 : bn2 + 1;
    }
    asm volatile("s_waitcnt vmcnt(4)" ::: "memory");
    __builtin_amdgcn_s_barrier();
    compute(bc);
    bc = (bc == 2) ? 0 : bc + 1;
    asm volatile("s_waitcnt vmcnt(0)" ::: "memory");
    __builtin_amdgcn_s_barrier();
    compute(bc);

    float part[4] = {0.f, 0.f, 0.f, 0.f};
#pragma unroll
    for (int n = 0; n < 4; ++n) {
        int col = n * 16 + l15;
        float b1 = h1b[t * H_ + col];
        float w2 = h2w[t * H_ + col];
#pragma unroll
        for (int j = 0; j < 4; ++j) part[j] += (acc[n][j] + b1) * w2;
    }
#pragma unroll
    for (int msk = 1; msk < 16; msk <<= 1)
#pragma unroll
        for (int j = 0; j < 4; ++j) part[j] += __shfl_xor(part[j], msk);
    if (l15 == 0) {
        float b2 = h2b[t];
#pragma unroll
        for (int j = 0; j < 4; ++j) {
            int row = m0 + wid * 16 + l4 * 4 + j;
            if (row < mend) {
                int orig = perm[row];
                out[orig] = 1.f / (1.f + expf(-(part[j] + b2)));
            }
        }
    }
}

// ---------------------------------------------------------------------------
extern "C" void kernel_launch(void* const* d_in, const int* in_sizes, int n_in,
                              void* d_out, int out_size, void* d_ws, size_t ws_size,
                              hipStream_t stream) {
    (void)in_sizes; (void)n_in; (void)out_size;
    if (ws_size < WS_NEED) return;   // visible clean-fail if scratch too small

    const float* x    = (const float*)d_in[0];
    const int*   bt   = (const int*)d_in[1];
    const float* ws1W = (const float*)d_in[2];
    const float* ws1b = (const float*)d_in[3];
    const float* wt1W = (const float*)d_in[4];
    const float* wt1b = (const float*)d_in[5];
    const float* ws2W = (const float*)d_in[6];
    const float* ws2b = (const float*)d_in[7];
    const float* wt2W = (const float*)d_in[8];
    const float* wt2b = (const float*)d_in[9];
    const float* h1W  = (const float*)d_in[10];
    const float* h1b  = (const float*)d_in[11];
    const float* h2W  = (const float*)d_in[12];
    const float* h2b  = (const float*)d_in[13];

    char* ws = (char*)d_ws;
    int* perm = (int*)(ws + OFF_PERM);
    int* seg  = (int*)(ws + OFF_SEG);
    unsigned short* wb = (unsigned short*)(ws + OFF_W);
    unsigned short* xp = (unsigned short*)(ws + OFF_XP);
    unsigned short* a0 = (unsigned short*)(ws + OFF_A0);
    unsigned short* a1 = (unsigned short*)(ws + OFF_A1);

    perm_kernel<<<1, 256, 0, stream>>>(bt, perm, seg);
    transpose_cvt<<<dim3(16, 16, 24), 256, 0, stream>>>(ws1W, wt1W, ws2W, wt2W, h1W, wb);
    gather_x<<<B_, 256, 0, stream>>>(x, perm, xp);

    // 1D grids: bid%8 controls XCD; mapping inside the kernel.
    // shared1: lin, then relu->lin  (relu folded into producer epilogue)
    gemm_pass<true,  false><<<512, 256, 0, stream>>>(xp, wb + 0 * MSZ,  ws1b + 0,  a0, seg, 0, 0);
    gemm_pass<true,  false><<<512, 256, 0, stream>>>(a0, wb + 1 * MSZ,  ws1b + D_, a1, seg, 0, 0);
    // task1: (relu->lin)x2 ; second layer output feeds shared2 RAW -> no relu
    gemm_pass<true,  true ><<<2048, 256, 0, stream>>>(a1, wb + 2 * MSZ,  wt1b + 0,  a0, seg, 2 * MSZ, 2 * D_);
    gemm_pass<false, true ><<<2048, 256, 0, stream>>>(a0, wb + 3 * MSZ,  wt1b + D_, a1, seg, 2 * MSZ, 2 * D_);
    // shared2
    gemm_pass<true,  false><<<512, 256, 0, stream>>>(a1, wb + 10 * MSZ, ws2b + 0,  a0, seg, 0, 0);
    gemm_pass<true,  false><<<512, 256, 0, stream>>>(a0, wb + 11 * MSZ, ws2b + D_, a1, seg, 0, 0);
    // task2 body
    gemm_pass<true,  true ><<<2048, 256, 0, stream>>>(a1, wb + 12 * MSZ, wt2b + 0,  a0, seg, 2 * MSZ, 2 * D_);
    gemm_pass<true,  true ><<<2048, 256, 0, stream>>>(a0, wb + 13 * MSZ, wt2b + D_, a1, seg, 2 * MSZ, 2 * D_);
    // head: D->64 (+bias, no relu), dot h2, sigmoid, scatter
    head_pass<<<dim3(128), 256, 0, stream>>>(a1, wb + H1T_ELEM_OFF, h1b, h2W, h2b, seg, perm, (float*)d_out);
}

// Round 12
// 256.837 us; speedup vs baseline: 5.1239x; 1.1761x over previous
//
#include <hip/hip_runtime.h>

// ---------------------------------------------------------------------------
// multitask MLP, MI355X bf16 MFMA — round 10 (2nd resubmit; r10/r11 benches
// lost to infra failures, no data)
// r9 post-mortem: r8 (XCD-affinity + depth-3, bundled) regressed 271->302;
// both reverted. Model: staging service is L3/cross-XCD-bound; staged bytes
// per pass = 4096/BN + 4096/BM MB. Single change vs r5:
//   BM=64 BN=128, 8 waves (512 thr), grid 256 (1 block/CU, 2 waves/SIMD =
//   same TLP as r5), staged bytes 128->96 MB (0.75x). Pipeline depth 2,
//   counted vmcnt(3), 1 raw barrier/step, XOR slot-swizzle kept verbatim.
// ---------------------------------------------------------------------------

typedef __attribute__((ext_vector_type(4))) float f32x4;
typedef __attribute__((ext_vector_type(8))) __bf16 bf16x8;
typedef __attribute__((ext_vector_type(4))) unsigned short u16x4;

#define AS1 __attribute__((address_space(1)))
#define AS3 __attribute__((address_space(3)))

static constexpr int B_  = 2048;
static constexpr int D_  = 1024;
static constexpr int T_  = 4;
static constexpr int H_  = 64;
static constexpr int MP_ = 2112;                    // B_ padded for tile overrun
static constexpr size_t MSZ = (size_t)D_ * D_;      // elems per DxD matrix (1M)

// ws layout (bytes)
static constexpr size_t OFF_PERM = 0;                         // 2048 int
static constexpr size_t OFF_SEG  = 8192;                      // 8 int
static constexpr size_t OFF_W    = 16384;                     // bf16 transposed weights
//   matrices 0..1: ws1 l0,l1 | 2..9: wt1 (t*2+l) | 10..11: ws2 | 12..19: wt2 (t*2+l)
//   then h1t: 4 * [64][1024]
static constexpr size_t H1T_ELEM_OFF = 20 * MSZ;
static constexpr size_t W_ELEMS  = 20 * MSZ + (size_t)T_ * H_ * D_;
static constexpr size_t OFF_XP   = OFF_W + W_ELEMS * 2;
static constexpr size_t ACT_BYTES = (size_t)MP_ * D_ * 2;
static constexpr size_t OFF_A0   = OFF_XP + ACT_BYTES;
static constexpr size_t OFF_A1   = OFF_A0 + ACT_BYTES;
static constexpr size_t WS_NEED  = OFF_A1 + ACT_BYTES;        // ~53 MiB

static __device__ __forceinline__ unsigned short f2bf(float f) {
    union { float f; unsigned int u; } v; v.f = f;
    unsigned int r = v.u + 0x7fffu + ((v.u >> 16) & 1u);      // RNE
    return (unsigned short)(r >> 16);
}

// ---------------------------------------------------------------------------
// 1) per-task segments + permutation (1 block)
// ---------------------------------------------------------------------------
__global__ void perm_kernel(const int* __restrict__ btask,
                            int* __restrict__ perm, int* __restrict__ seg) {
    __shared__ int cnt[T_], cur[T_];
    int tid = threadIdx.x;
    if (tid < T_) cnt[tid] = 0;
    __syncthreads();
    for (int i = tid; i < B_; i += 256) atomicAdd(&cnt[btask[i]], 1);
    __syncthreads();
    if (tid == 0) {
        int s = 0;
        for (int t = 0; t < T_; ++t) {
            seg[t] = s; seg[T_ + t] = cnt[t]; cur[t] = s; s += cnt[t];
        }
    }
    __syncthreads();
    for (int i = tid; i < B_; i += 256) {
        int t = btask[i];
        int p = atomicAdd(&cur[t], 1);
        perm[p] = i;
    }
}

// ---------------------------------------------------------------------------
// 2) fp32 -> bf16 transpose of all weight matrices.  z: matrix id 0..23.
// ---------------------------------------------------------------------------
__global__ __launch_bounds__(256)
void transpose_cvt(const float* __restrict__ ws1, const float* __restrict__ wt1,
                   const float* __restrict__ ws2, const float* __restrict__ wt2,
                   const float* __restrict__ h1, unsigned short* __restrict__ wb) {
    int z = blockIdx.z;
    const float* src; unsigned short* dst; int C = D_;
    if (z < 2)       { src = ws1 + (size_t)z * MSZ;        dst = wb + (size_t)z * MSZ; }
    else if (z < 10) { src = wt1 + (size_t)(z - 2) * MSZ;  dst = wb + (size_t)z * MSZ; }
    else if (z < 12) { src = ws2 + (size_t)(z - 10) * MSZ; dst = wb + (size_t)z * MSZ; }
    else if (z < 20) { src = wt2 + (size_t)(z - 12) * MSZ; dst = wb + (size_t)z * MSZ; }
    else { src = h1 + (size_t)(z - 20) * (D_ * H_);
           dst = wb + H1T_ELEM_OFF + (size_t)(z - 20) * (D_ * H_); C = H_; }
    int r0 = blockIdx.y * 64, c0 = blockIdx.x * 64;
    if (c0 >= C) return;
    __shared__ float tile[64][65];
    int tid = threadIdx.x;
#pragma unroll
    for (int i = 0; i < 4; ++i) {
        int idx = i * 256 + tid;
        int fr = idx >> 4, fc = (idx & 15) << 2;
        float4 v = *(const float4*)(src + (size_t)(r0 + fr) * C + c0 + fc);
        tile[fr][fc] = v.x; tile[fr][fc + 1] = v.y; tile[fr][fc + 2] = v.z; tile[fr][fc + 3] = v.w;
    }
    __syncthreads();
#pragma unroll
    for (int i = 0; i < 4; ++i) {
        int idx = i * 256 + tid;
        int orow = idx >> 4, ocb = (idx & 15) << 2;
        u16x4 o = { f2bf(tile[ocb][orow]),     f2bf(tile[ocb + 1][orow]),
                    f2bf(tile[ocb + 2][orow]), f2bf(tile[ocb + 3][orow]) };
        *(u16x4*)(dst + (size_t)(c0 + orow) * D_ + r0 + ocb) = o;
    }
}

// ---------------------------------------------------------------------------
// 3) gather x into permuted order, convert to bf16.  1 block = 1 row.
// ---------------------------------------------------------------------------
__global__ void gather_x(const float* __restrict__ x, const int* __restrict__ perm,
                         unsigned short* __restrict__ xp) {
    int pos = blockIdx.x;
    int src = perm[pos];
    int t = threadIdx.x;                       // 256 threads * 4 floats
    float4 v = *((const float4*)(x + (size_t)src * D_) + t);
    u16x4 o = { f2bf(v.x), f2bf(v.y), f2bf(v.z), f2bf(v.w) };
    *((u16x4*)(xp + (size_t)pos * D_) + t) = o;
}

// ---------------------------------------------------------------------------
// 4) GEMM pass: BM=64 BN=128 BK=64, 8 waves (2x4), wave tile 32x32.
//    Staged/pass = 96 MB (vs r5 128).  3 LDS buffers, 2-deep prefetch,
//    24 staging chunks/step (8 A + 16 B) = 3 per wave, steady vmcnt(3),
//    one raw s_barrier per k-step:
//      iter t: vmcnt(3) [stage(t) landed] -> barrier -> stage(t+2) -> compute(t)
//    XOR slot-swizzle: LDS dest linear; global source slot (L&7)^(L>>3);
//    ds_read k-slot (kk*4+l4)^(l15&7).
// ---------------------------------------------------------------------------
template<bool RELU, bool TASK>
__global__ __launch_bounds__(512, 1)
void gemm_pass(const unsigned short* __restrict__ A, const unsigned short* __restrict__ W,
               const float* __restrict__ bias, unsigned short* __restrict__ Out,
               const int* __restrict__ seg, size_t wstride, size_t bstride) {
    __shared__ unsigned short lA[3][64 * 64];      // 3 x  8 KB
    __shared__ unsigned short lB[3][128 * 64];     // 3 x 16 KB   (72 KB total)
    int m0, mend, t = 0;
    if (TASK) {
        t = blockIdx.y / 9;
        int mt = blockIdx.y % 9;
        int s = seg[t], c = seg[4 + t];
        m0 = s + mt * 64; mend = s + c;
        if (m0 >= mend) return;
    } else { m0 = blockIdx.y * 64; mend = B_; }
    const unsigned short* Wt = W + (size_t)t * wstride;
    const float* bs = bias + (size_t)t * bstride;
    const int n0 = blockIdx.x * 128;

    const int tid = threadIdx.x, wid = tid >> 6, lane = tid & 63;
    const int wm = wid >> 2, wn = wid & 3;         // 2 x 4 wave grid
    const int l15 = lane & 15, l4 = lane >> 4;
    const int srow = lane >> 3;                    // 0..7 within staging chunk
    const int sslot = ((lane & 7) ^ srow) * 16;    // pre-swizzled source slot (bytes)

    f32x4 acc[2][2] = {};

    auto stage = [&](int kt, int buf) {
        const int k0 = kt * 64;
#pragma unroll
        for (int i = 0; i < 3; ++i) {              // 24 chunks total, 3 per wave
            int c = wid * 3 + i;                   // 0..23
            const char* src; unsigned short* dst;
            if (c < 8) {                           // A chunk: rows c*8..c*8+7
                src = (const char*)(A + (size_t)(m0 + c * 8 + srow) * D_ + k0) + sslot;
                dst = &lA[buf][0] + (size_t)c * 512;
            } else {                               // B chunk
                int cb = c - 8;
                src = (const char*)(Wt + (size_t)(n0 + cb * 8 + srow) * D_ + k0) + sslot;
                dst = &lB[buf][0] + (size_t)cb * 512;
            }
            __builtin_amdgcn_global_load_lds((AS1 void*)src, (AS3 void*)dst, 16, 0, 0);
        }
    };

    auto compute = [&](int buf) {
        const unsigned short* bA = &lA[buf][0];
        const unsigned short* bB = &lB[buf][0];
#pragma unroll
        for (int kk = 0; kk < 2; ++kk) {
            const int swz = (((kk * 4) + l4) ^ (l15 & 7)) * 8;   // swizzled k-offset (elems)
            bf16x8 af[2], bfr[2];
#pragma unroll
            for (int m = 0; m < 2; ++m)
                af[m] = *(const bf16x8*)(bA + (wm * 32 + m * 16 + l15) * 64 + swz);
#pragma unroll
            for (int n = 0; n < 2; ++n)
                bfr[n] = *(const bf16x8*)(bB + (wn * 32 + n * 16 + l15) * 64 + swz);
#pragma unroll
            for (int m = 0; m < 2; ++m)
#pragma unroll
                for (int n = 0; n < 2; ++n)
                    acc[m][n] = __builtin_amdgcn_mfma_f32_16x16x32_bf16(af[m], bfr[n], acc[m][n], 0, 0, 0);
        }
    };

    stage(0, 0);
    stage(1, 1);
    int bc = 0, bn2 = 2;
#pragma unroll 1
    for (int kt = 0; kt < 14; ++kt) {              // 16 k-steps total, 2 peeled
        asm volatile("s_waitcnt vmcnt(3)" ::: "memory");   // stage(kt) landed
        __builtin_amdgcn_s_barrier();
        stage(kt + 2, bn2);
        compute(bc);
        bc  = (bc  == 2) ? 0 : bc  + 1;
        bn2 = (bn2 == 2) ? 0 : bn2 + 1;
    }
    asm volatile("s_waitcnt vmcnt(3)" ::: "memory");
    __builtin_amdgcn_s_barrier();
    compute(bc);
    bc = (bc == 2) ? 0 : bc + 1;
    asm volatile("s_waitcnt vmcnt(0)" ::: "memory");
    __builtin_amdgcn_s_barrier();
    compute(bc);

    // epilogue: C/D layout col=lane&15, row=(lane>>4)*4+j  [guide §3, m89-verified]
#pragma unroll
    for (int n = 0; n < 2; ++n) {
        int col = n0 + wn * 32 + n * 16 + l15;
        float bv = bs[col];
#pragma unroll
        for (int m = 0; m < 2; ++m) {
            int rbase = m0 + wm * 32 + m * 16 + l4 * 4;
#pragma unroll
            for (int j = 0; j < 4; ++j) {
                int row = rbase + j;
                if (!TASK || row < mend) {
                    float v = acc[m][n][j] + bv;
                    if (RELU) v = fmaxf(v, 0.f);
                    Out[(size_t)row * D_ + col] = f2bf(v);
                }
            }
        }
    }
}

// ---------------------------------------------------------------------------
// 5) head (r5-proven): 4 waves, 3-buf pipeline vmcnt(4): r = A @ H1t[t] + h1_b
//    (no relu), logit = r . h2_W[t] + h2_b[t], out[orig] = sigmoid(logit).
// ---------------------------------------------------------------------------
__global__ __launch_bounds__(256)
void head_pass(const unsigned short* __restrict__ A, const unsigned short* __restrict__ H1t,
               const float* __restrict__ h1b, const float* __restrict__ h2w,
               const float* __restrict__ h2b, const int* __restrict__ seg,
               const int* __restrict__ perm, float* __restrict__ out) {
    __shared__ unsigned short lA[3][4096];
    __shared__ unsigned short lB[3][4096];         // 48 KB total
    int t = blockIdx.x >> 5, mt = blockIdx.x & 31;
    int s = seg[t], c = seg[4 + t];
    int m0 = s + mt * 64, mend = s + c;
    if (m0 >= mend) return;
    const unsigned short* Ht = H1t + (size_t)t * (H_ * D_);
    const int tid = threadIdx.x, wid = tid >> 6, lane = tid & 63;
    const int l15 = lane & 15, l4 = lane >> 4;
    const int srow = lane >> 3;
    const int sslot = ((lane & 7) ^ srow) * 16;
    f32x4 acc[4] = {};

    auto stage = [&](int kt, int buf) {
        const int k0 = kt * 64;
#pragma unroll
        for (int i = 0; i < 2; ++i) {
            int chunk = wid * 2 + i;
            int row = chunk * 8 + srow;
            const char* sa = (const char*)(A + (size_t)(m0 + row) * D_ + k0) + sslot;
            __builtin_amdgcn_global_load_lds((AS1 void*)sa,
                (AS3 void*)(&lA[buf][0] + (size_t)chunk * 512), 16, 0, 0);
            const char* sb = (const char*)(Ht + (size_t)row * D_ + k0) + sslot;
            __builtin_amdgcn_global_load_lds((AS1 void*)sb,
                (AS3 void*)(&lB[buf][0] + (size_t)chunk * 512), 16, 0, 0);
        }
    };
    auto compute = [&](int buf) {
#pragma unroll
        for (int kk = 0; kk < 2; ++kk) {
            const int swz = (((kk * 4) + l4) ^ (l15 & 7)) * 8;
            bf16x8 af = *(const bf16x8*)(&lA[buf][0] + (wid * 16 + l15) * 64 + swz);
#pragma unroll
            for (int n = 0; n < 4; ++n) {
                bf16x8 bfr = *(const bf16x8*)(&lB[buf][0] + (n * 16 + l15) * 64 + swz);
                acc[n] = __builtin_amdgcn_mfma_f32_16x16x32_bf16(af, bfr, acc[n], 0, 0, 0);
            }
        }
    };

    stage(0, 0);
    stage(1, 1);
    int bc = 0, bn2 = 2;
#pragma unroll 1
    for (int kt = 0; kt < 14; ++kt) {
        asm volatile("s_waitcnt vmcnt(4)" ::: "memory");
        __builtin_amdgcn_s_barrier();
        stage(kt + 2, bn2);
        compute(bc);
        bc  = (bc  == 2) ? 0 : bc  + 1;
        bn2 = (bn2 == 2) ? 0 : bn2 + 1;
    }
    asm volatile("s_waitcnt vmcnt(4)" ::: "memory");
    __builtin_amdgcn_s_barrier();
    compute(bc);
    bc = (bc == 2) ? 0 : bc + 1;
    asm volatile("s_waitcnt vmcnt(0)" ::: "memory");
    __builtin_amdgcn_s_barrier();
    compute(bc);

    float part[4] = {0.f, 0.f, 0.f, 0.f};
#pragma unroll
    for (int n = 0; n < 4; ++n) {
        int col = n * 16 + l15;
        float b1 = h1b[t * H_ + col];
        float w2 = h2w[t * H_ + col];
#pragma unroll
        for (int j = 0; j < 4; ++j) part[j] += (acc[n][j] + b1) * w2;
    }
#pragma unroll
    for (int msk = 1; msk < 16; msk <<= 1)
#pragma unroll
        for (int j = 0; j < 4; ++j) part[j] += __shfl_xor(part[j], msk);
    if (l15 == 0) {
        float b2 = h2b[t];
#pragma unroll
        for (int j = 0; j < 4; ++j) {
            int row = m0 + wid * 16 + l4 * 4 + j;
            if (row < mend) {
                int orig = perm[row];
                out[orig] = 1.f / (1.f + expf(-(part[j] + b2)));
            }
        }
    }
}

// ---------------------------------------------------------------------------
extern "C" void kernel_launch(void* const* d_in, const int* in_sizes, int n_in,
                              void* d_out, int out_size, void* d_ws, size_t ws_size,
                              hipStream_t stream) {
    (void)in_sizes; (void)n_in; (void)out_size;
    if (ws_size < WS_NEED) return;   // visible clean-fail if scratch too small

    const float* x    = (const float*)d_in[0];
    const int*   bt   = (const int*)d_in[1];
    const float* ws1W = (const float*)d_in[2];
    const float* ws1b = (const float*)d_in[3];
    const float* wt1W = (const float*)d_in[4];
    const float* wt1b = (const float*)d_in[5];
    const float* ws2W = (const float*)d_in[6];
    const float* ws2b = (const float*)d_in[7];
    const float* wt2W = (const float*)d_in[8];
    const float* wt2b = (const float*)d_in[9];
    const float* h1W  = (const float*)d_in[10];
    const float* h1b  = (const float*)d_in[11];
    const float* h2W  = (const float*)d_in[12];
    const float* h2b  = (const float*)d_in[13];

    char* ws = (char*)d_ws;
    int* perm = (int*)(ws + OFF_PERM);
    int* seg  = (int*)(ws + OFF_SEG);
    unsigned short* wb = (unsigned short*)(ws + OFF_W);
    unsigned short* xp = (unsigned short*)(ws + OFF_XP);
    unsigned short* a0 = (unsigned short*)(ws + OFF_A0);
    unsigned short* a1 = (unsigned short*)(ws + OFF_A1);

    perm_kernel<<<1, 256, 0, stream>>>(bt, perm, seg);
    transpose_cvt<<<dim3(16, 16, 24), 256, 0, stream>>>(ws1W, wt1W, ws2W, wt2W, h1W, wb);
    gather_x<<<B_, 256, 0, stream>>>(x, perm, xp);

    dim3 gs(8, 32), gt(8, 36);                     // BN=128 -> 8 n-tiles
    // shared1: lin, then relu->lin  (relu folded into producer epilogue)
    gemm_pass<true,  false><<<gs, 512, 0, stream>>>(xp, wb + 0 * MSZ,  ws1b + 0,  a0, seg, 0, 0);
    gemm_pass<true,  false><<<gs, 512, 0, stream>>>(a0, wb + 1 * MSZ,  ws1b + D_, a1, seg, 0, 0);
    // task1: (relu->lin)x2 ; second layer output feeds shared2 RAW -> no relu
    gemm_pass<true,  true ><<<gt, 512, 0, stream>>>(a1, wb + 2 * MSZ,  wt1b + 0,  a0, seg, 2 * MSZ, 2 * D_);
    gemm_pass<false, true ><<<gt, 512, 0, stream>>>(a0, wb + 3 * MSZ,  wt1b + D_, a1, seg, 2 * MSZ, 2 * D_);
    // shared2
    gemm_pass<true,  false><<<gs, 512, 0, stream>>>(a1, wb + 10 * MSZ, ws2b + 0,  a0, seg, 0, 0);
    gemm_pass<true,  false><<<gs, 512, 0, stream>>>(a0, wb + 11 * MSZ, ws2b + D_, a1, seg, 0, 0);
    // task2 body
    gemm_pass<true,  true ><<<gt, 512, 0, stream>>>(a1, wb + 12 * MSZ, wt2b + 0,  a0, seg, 2 * MSZ, 2 * D_);
    gemm_pass<true,  true ><<<gt, 512, 0, stream>>>(a0, wb + 13 * MSZ, wt2b + D_, a1, seg, 2 * MSZ, 2 * D_);
    // head: D->64 (+bias, no relu), dot h2, sigmoid, scatter
    head_pass<<<dim3(128), 256, 0, stream>>>(a1, wb + H1T_ELEM_OFF, h1b, h2W, h2b, seg, perm, (float*)d_out);
}